// Round 8
// baseline (54203.131 us; speedup 1.0000x reference)
//
#include <hip/hip_runtime.h>
#include <math.h>

#define SEQ 8192
#define IN_DIM 128
#define HID 512
#define OUT_DIM 128
#define NK 9      // 8 spline basis + 1 silu slot
#define KNOTS 12

// ws layout (floats). W9HU region reused for W9O by build2 (after seq).
#define WS_ELECT 0                           // [0]=ticket, [1..32]=slot xcc (u32)
#define WS_W9HU  64                          // 128*9*512 = 589,824 (xpart W); later W9O (512*9*128)
#define WS_WSEQ  (WS_W9HU + 589824)          // 32*128*4*4*4*9 = 2,359,296 (seq W: [blk][q][oq][r][j][k])
#define WS_XPART (WS_WSEQ + 2359296)         // 8192*512
#define WS_HCOMM (WS_XPART + 4194304)        // 8192*512
#define WS_TOTAL (WS_HCOMM + 4194304)        // ~45.4 MB

#define SENTINEL 0x7FA0DEADu   // sNaN payload; never produced by arithmetic
#define SLOT_INIT 0xFFFFFFFFu

#define NWG 32
#define TPB2 512
#define NB_LAUNCH 512

__device__ __forceinline__ int brow(int ib) { return ib*3 + (ib >> 4); }  // R2-proven (stride-16 reads)
// bijective row permutation for seq LDS: spreads 12-float-stride rows across banks.
__device__ __forceinline__ int rho(int i) { return i ^ ((i >> 4) & 7); }

// L1-bypassing load: hits this XCD's L2 (same-XCD coherence point)
__device__ __forceinline__ unsigned ld_sc0(const unsigned* p) {
    unsigned r;
    asm volatile("global_load_dword %0, %1, off sc0\n\ts_waitcnt vmcnt(0)"
                 : "=v"(r) : "v"(p) : "memory");
    return r;
}

__device__ __forceinline__ void load_knots(const float* gptr, float* g, float* invA) {
    #pragma unroll
    for (int j = 0; j < KNOTS; ++j) g[j] = gptr[j];
    #pragma unroll
    for (int d = 1; d <= 3; ++d) {
        #pragma unroll
        for (int j = 0; j < 11; ++j) {
            if (j + d <= 11) invA[(d-1)*11 + j] = 1.0f / (g[j+d] - g[j]);
        }
    }
}

// Exact Cox-de Boor (degree 3) + silu — parallel kernels (R2-proven)
__device__ __forceinline__ void basis9(float x, const float* g, const float* invA, float* out) {
    float B[11];
    #pragma unroll
    for (int j = 0; j < 11; ++j)
        B[j] = (x >= g[j] && x < g[j+1]) ? 1.0f : 0.0f;
    #pragma unroll
    for (int d = 1; d <= 3; ++d) {
        #pragma unroll
        for (int j = 0; j < 11; ++j) {
            if (j + d < 11) {
                float left  = (x - g[j]) * invA[(d-1)*11 + j];
                float right = (g[j+d+1] - x) * invA[(d-1)*11 + j + 1];
                B[j] = left * B[j] + right * B[j+1];
            }
        }
    }
    #pragma unroll
    for (int j = 0; j < 8; ++j) out[j] = B[j];
    out[8] = x / (1.0f + expf(-x));
}

// ---------------- build1: election init + xpart weights + seq weights + sentinel fill ----------------
__global__ __launch_bounds__(256) void build1_kernel(
    const float* __restrict__ hu_coef, const float* __restrict__ hu_sb, const float* __restrict__ hu_ssp,
    float* __restrict__ ws)
{
    int idx = blockIdx.x * blockDim.x + threadIdx.x;
    int stride = gridDim.x * blockDim.x;
    if (idx == 0) ((unsigned*)ws)[0] = 0u;
    else if (idx <= 32) ((unsigned*)ws)[idx] = SLOT_INIT;
    const int N1 = 128 * 9 * 512;
    for (int p = idx; p < N1; p += stride) {
        int o = p & 511; int k = (p >> 9) % 9; int i = p / 4608;
        float v = (k < 8) ? hu_ssp[i*HID + o] * hu_coef[(i*HID + o)*8 + k] : hu_sb[i*HID + o];
        ws[WS_W9HU + p] = v;
    }
    const int N2 = 32 * 128 * 4 * 4 * 4 * 9;
    for (int p = idx; p < N2; p += stride) {
        int k = p % 9; int rest = p / 9;
        int j = rest & 3; rest >>= 2;
        int r = rest & 3; rest >>= 2;
        int oq = rest & 3; rest >>= 2;
        int q = rest & 127; int blk = rest >> 7;
        int gi = IN_DIM + 4*q + r;
        int o  = blk*16 + oq*4 + j;
        float v = (k < 8) ? hu_ssp[gi*HID + o] * hu_coef[(gi*HID + o)*8 + k] : hu_sb[gi*HID + o];
        ws[WS_WSEQ + p] = v;
    }
    unsigned* hc = (unsigned*)(ws + WS_HCOMM);
    for (int p = idx; p < SEQ*HID; p += stride) hc[p] = SENTINEL;
}

// ---------------- build2: output-layer weights (overlays W9HU; runs after seq) ----------------
__global__ __launch_bounds__(256) void build2_kernel(
    const float* __restrict__ out_coef, const float* __restrict__ out_sb, const float* __restrict__ out_ssp,
    float* __restrict__ ws)
{
    int idx = blockIdx.x * blockDim.x + threadIdx.x;
    int stride = gridDim.x * blockDim.x;
    const int N = 512 * 9 * 128;   // [i<512][k<9][o<128]
    for (int p = idx; p < N; p += stride) {
        int o = p & 127; int k = (p >> 7) % 9; int i = p / 1152;
        float v = (k < 8) ? out_ssp[i*OUT_DIM + o] * out_coef[(i*OUT_DIM + o)*8 + k] : out_sb[i*OUT_DIM + o];
        ws[WS_W9HU + p] = v;
    }
}

// ---------------- phase 1: x-part contributions (R2-proven form) ----------------
#define R1 4
__global__ __launch_bounds__(256) void xpart_kernel(
    const float* __restrict__ X, const float* __restrict__ hu_grid, float* __restrict__ ws)
{
    const int tid = threadIdx.x;
    const int t0 = blockIdx.x * R1;
    const float* W9 = ws + WS_W9HU;
    float* xpart = ws + WS_XPART;
    float g[KNOTS], invA[33];
    load_knots(hu_grid, g, invA);

    __shared__ float4 bas4[R1*IN_DIM*3 + (R1*IN_DIM)/16];
    #pragma unroll
    for (int rep = 0; rep < 2; ++rep) {
        int idx = tid + rep*256;
        int r = idx >> 7, i = idx & 127;
        float bv[9];
        basis9(X[(t0 + r)*IN_DIM + i], g, invA, bv);
        int rb = brow(idx);
        bas4[rb]   = make_float4(bv[0], bv[1], bv[2], bv[3]);
        bas4[rb+1] = make_float4(bv[4], bv[5], bv[6], bv[7]);
        bas4[rb+2] = make_float4(bv[8], 0.f, 0.f, 0.f);
    }
    __syncthreads();

    float acc[R1][2];
    #pragma unroll
    for (int r = 0; r < R1; ++r) { acc[r][0] = 0.f; acc[r][1] = 0.f; }

    for (int i = 0; i < IN_DIM; ++i) {
        float w1[9], w2[9];
        #pragma unroll
        for (int k = 0; k < 9; ++k) {
            w1[k] = W9[(i*NK+k)*HID + tid];
            w2[k] = W9[(i*NK+k)*HID + tid + 256];
        }
        #pragma unroll
        for (int r = 0; r < R1; ++r) {
            const float* rp = (const float*)&bas4[brow(r*IN_DIM + i)];
            float4 b0 = ((const float4*)rp)[0], b1 = ((const float4*)rp)[1];
            float b8 = rp[8];
            float s1 = w1[0]*b0.x + w1[1]*b0.y + w1[2]*b0.z + w1[3]*b0.w
                     + w1[4]*b1.x + w1[5]*b1.y + w1[6]*b1.z + w1[7]*b1.w + w1[8]*b8;
            float s2 = w2[0]*b0.x + w2[1]*b0.y + w2[2]*b0.z + w2[3]*b0.w
                     + w2[4]*b1.x + w2[5]*b1.y + w2[6]*b1.z + w2[7]*b1.w + w2[8]*b8;
            acc[r][0] += s1; acc[r][1] += s2;
        }
    }
    #pragma unroll
    for (int r = 0; r < R1; ++r) {
        xpart[(t0+r)*HID + tid]       = acc[r][0];
        xpart[(t0+r)*HID + tid + 256] = acc[r][1];
    }
}

// ---------------- phase 2: sequential recurrence (same-XCD cluster; dual-store publish) ----------------
__global__ __launch_bounds__(TPB2, 1) void seq_kernel(
    const float* __restrict__ h0, const float* __restrict__ hu_grid,
    float* __restrict__ ws, float* __restrict__ d_out)
{
    __shared__ int sh_slot, sh_mode;
    __shared__ float basf[512*12];          // rho-permuted rows, stride 12 floats (16B-aligned)
    __shared__ float red[8][4][4];

    const int tid = threadIdx.x;
    unsigned* el = (unsigned*)ws;

    if (tid == 0) {
        unsigned xcc;
        asm volatile("s_getreg_b32 %0, hwreg(HW_REG_XCC_ID)" : "=s"(xcc));
        int slot = 64;
        if (xcc == 0u) {
            slot = (int)__hip_atomic_fetch_add(&el[0], 1u, __ATOMIC_RELAXED, __HIP_MEMORY_SCOPE_AGENT);
        } else {
            unsigned long long tc0 = __builtin_amdgcn_s_memrealtime();
            while (__builtin_amdgcn_s_memrealtime() - tc0 < 2500ull) {}   // ~25us, time-based only
            unsigned c = __hip_atomic_load(&el[0], __ATOMIC_RELAXED, __HIP_MEMORY_SCOPE_AGENT);
            if (c < (unsigned)NWG)
                slot = (int)__hip_atomic_fetch_add(&el[0], 1u, __ATOMIC_RELAXED, __HIP_MEMORY_SCOPE_AGENT);
        }
        int mode = 0;
        if (slot < NWG) {
            __hip_atomic_store(&el[1+slot], xcc, __ATOMIC_RELAXED, __HIP_MEMORY_SCOPE_AGENT);
            int ok = 1; unsigned first = 0;
            for (int i = 0; i < NWG; ++i) {
                unsigned v; int sp = 0;
                do { v = __hip_atomic_load(&el[1+i], __ATOMIC_RELAXED, __HIP_MEMORY_SCOPE_AGENT); }
                while (v == SLOT_INIT && ++sp < (1 << 20));
                if (v == SLOT_INIT) { ok = 0; break; }
                if (i == 0) first = v;
                else if (v != first) { ok = 0; break; }
            }
            mode = ok;
        }
        sh_slot = slot; sh_mode = mode;
    }
    __syncthreads();
    const int blk = sh_slot;
    const int mode = sh_mode;
    if (blk >= NWG) return;

    const int lane = tid & 63;
    const int wave = tid >> 6;
    const int oq   = tid & 3;        // output quad (4-way broadcast rows)
    const int q    = tid >> 2;       // input quad 0..127
    const float* xpart = ws + WS_XPART;
    float* hcomm = ws + WS_HCOMM;
    float* hs_out = d_out + (size_t)SEQ*OUT_DIM;
    const float g0 = hu_grid[0];
    const float inv_h = 1.0f / (hu_grid[1] - hu_grid[0]);

    // register-resident weights (VGPR cap 256 at 1 wave-group/CU)
    float w[4][4][9];
    {
        const float* Wb = ws + WS_WSEQ + ((size_t)((blk*128 + q)*4 + oq))*144;
        #pragma unroll
        for (int r = 0; r < 4; ++r)
            #pragma unroll
            for (int j = 0; j < 4; ++j)
                #pragma unroll
                for (int k = 0; k < 9; ++k)
                    w[r][j][k] = Wb[(r*4 + j)*9 + k];
    }

    for (int t = 0; t < SEQ; ++t) {
        float xf = (tid < 16) ? xpart[(size_t)t*HID + blk*16 + tid] : 0.0f;  // poll-independent

        float hv;
        if (t == 0) {
            hv = h0[tid];
        } else {
            const unsigned* pp = (const unsigned*)&hcomm[(size_t)(t-1)*HID + tid];
            unsigned u;
            if (mode) {
                u = ld_sc0(pp);
                int sp = 0;
                while (u == SENTINEL && ++sp < 64) u = ld_sc0(pp);    // local-L2 fast path (bounded)
            } else {
                u = __hip_atomic_load(pp, __ATOMIC_RELAXED, __HIP_MEMORY_SCOPE_AGENT);
            }
            int sp2 = 0;
            while (u == SENTINEL && ++sp2 < (1 << 24))                // always-correct fallback
                u = __hip_atomic_load(pp, __ATOMIC_RELAXED, __HIP_MEMORY_SCOPE_AGENT);
            hv = __uint_as_float(u);
        }

        // closed-form uniform cubic basis -> LDS row rho(tid), stride 12 floats
        {
            float* rowp = basf + rho(tid)*12;
            float tq = (hv - g0) * inv_h;
            float cf = floorf(tq);
            float u  = tq - cf;
            int   c  = (int)cf;
            float si = hv * __builtin_amdgcn_rcpf(1.0f + __expf(-hv));
            ((float4*)rowp)[0] = make_float4(0.f, 0.f, 0.f, 0.f);
            ((float4*)rowp)[1] = make_float4(0.f, 0.f, 0.f, 0.f);
            rowp[8] = si;
            if (c >= 0 && c <= 10) {
                float um = 1.0f - u, u2 = u*u, u3 = u2*u;
                float P0 = um*um*um*(1.0f/6.0f);
                float P1 = 0.5f*u3 - u2 + (2.0f/3.0f);
                float P2 = -0.5f*u3 + 0.5f*u2 + 0.5f*u + (1.0f/6.0f);
                float P3 = u3*(1.0f/6.0f);
                int j0 = c - 3;
                if (j0     >= 0)              rowp[j0]     = P0;
                if (j0 + 1 >= 0 && j0+1 <= 7) rowp[j0 + 1] = P1;
                if (j0 + 2 >= 0 && j0+2 <= 7) rowp[j0 + 2] = P2;
                if (j0 + 3 <= 7)              rowp[j0 + 3] = P3;
            }
        }
        __syncthreads();

        float p0 = 0.f, p1 = 0.f, p2 = 0.f, p3 = 0.f;
        #pragma unroll
        for (int r = 0; r < 4; ++r) {
            const float* rp = basf + rho(4*q + r)*12;
            float4 b0 = ((const float4*)rp)[0], b1 = ((const float4*)rp)[1];
            float b8 = rp[8];
            p0 += w[r][0][0]*b0.x + w[r][0][1]*b0.y + w[r][0][2]*b0.z + w[r][0][3]*b0.w
                + w[r][0][4]*b1.x + w[r][0][5]*b1.y + w[r][0][6]*b1.z + w[r][0][7]*b1.w + w[r][0][8]*b8;
            p1 += w[r][1][0]*b0.x + w[r][1][1]*b0.y + w[r][1][2]*b0.z + w[r][1][3]*b0.w
                + w[r][1][4]*b1.x + w[r][1][5]*b1.y + w[r][1][6]*b1.z + w[r][1][7]*b1.w + w[r][1][8]*b8;
            p2 += w[r][2][0]*b0.x + w[r][2][1]*b0.y + w[r][2][2]*b0.z + w[r][2][3]*b0.w
                + w[r][2][4]*b1.x + w[r][2][5]*b1.y + w[r][2][6]*b1.z + w[r][2][7]*b1.w + w[r][2][8]*b8;
            p3 += w[r][3][0]*b0.x + w[r][3][1]*b0.y + w[r][3][2]*b0.z + w[r][3][3]*b0.w
                + w[r][3][4]*b1.x + w[r][3][5]*b1.y + w[r][3][6]*b1.z + w[r][3][7]*b1.w + w[r][3][8]*b8;
        }
        #pragma unroll
        for (int d = 4; d < 64; d <<= 1) {
            p0 += __shfl_xor(p0, d, 64);
            p1 += __shfl_xor(p1, d, 64);
            p2 += __shfl_xor(p2, d, 64);
            p3 += __shfl_xor(p3, d, 64);
        }
        if (lane < 4) {
            red[wave][lane][0] = p0;
            red[wave][lane][1] = p1;
            red[wave][lane][2] = p2;
            red[wave][lane][3] = p3;
        }
        __syncthreads();
        if (tid < 16) {
            float s = xf;
            #pragma unroll
            for (int wv = 0; wv < 8; ++wv) s += red[wv][tid>>2][tid&3];
            unsigned su = __float_as_uint(s);
            unsigned* dst = (unsigned*)&hcomm[(size_t)t*HID + blk*16 + tid];
            *(volatile unsigned*)dst = su;   // fast path: lands in local L2 (L1 write-through)
            __hip_atomic_store(dst, su, __ATOMIC_RELAXED, __HIP_MEMORY_SCOPE_AGENT);  // IF$: always-correct
            hs_out[(size_t)t*HID + blk*16 + tid] = s;
        }
        __syncthreads();   // WAR: basf/red rewritten next step
    }
}

// ---------------- phase 3: output layer (R2-proven form) ----------------
#define R3 2
__global__ __launch_bounds__(256) void outlayer_kernel(
    const float* __restrict__ out_grid, float* __restrict__ ws, float* __restrict__ d_out)
{
    const int tid = threadIdx.x;
    const int t0 = blockIdx.x * R3;
    const float* W9o = ws + WS_W9HU;   // overlaid by build2
    const float* hs = d_out + (size_t)SEQ*OUT_DIM;
    float g[KNOTS], invA[33];
    load_knots(out_grid, g, invA);

    __shared__ float4 bas4[R3*HID*3 + (R3*HID)/16];
    #pragma unroll
    for (int rep = 0; rep < 4; ++rep) {
        int idx = tid + rep*256;
        int r = idx >> 9, i = idx & 511;
        float bv[9];
        basis9(hs[(size_t)(t0+r)*HID + i], g, invA, bv);
        int rb = brow(idx);
        bas4[rb]   = make_float4(bv[0], bv[1], bv[2], bv[3]);
        bas4[rb+1] = make_float4(bv[4], bv[5], bv[6], bv[7]);
        bas4[rb+2] = make_float4(bv[8], 0.f, 0.f, 0.f);
    }
    __syncthreads();

    const int oo = tid & 127;
    const int half = tid >> 7;
    float acc[R3] = {0.f, 0.f};
    for (int ii = 0; ii < 256; ++ii) {
        int i = half*256 + ii;
        float wv[9];
        #pragma unroll
        for (int k = 0; k < 9; ++k) wv[k] = W9o[(i*NK+k)*OUT_DIM + oo];
        #pragma unroll
        for (int r = 0; r < R3; ++r) {
            const float* rp = (const float*)&bas4[brow(r*HID + i)];
            float4 b0 = ((const float4*)rp)[0], b1 = ((const float4*)rp)[1];
            float b8 = rp[8];
            acc[r] += wv[0]*b0.x + wv[1]*b0.y + wv[2]*b0.z + wv[3]*b0.w
                    + wv[4]*b1.x + wv[5]*b1.y + wv[6]*b1.z + wv[7]*b1.w + wv[8]*b8;
        }
    }
    __shared__ float red[2][R3][128];
    red[half][0][oo] = acc[0];
    red[half][1][oo] = acc[1];
    __syncthreads();
    {
        int rr = tid >> 7, o2 = tid & 127;
        d_out[(size_t)(t0+rr)*OUT_DIM + o2] = red[0][rr][o2] + red[1][rr][o2];
    }
}

extern "C" void kernel_launch(void* const* d_in, const int* in_sizes, int n_in,
                              void* d_out, int out_size, void* d_ws, size_t ws_size,
                              hipStream_t stream) {
    (void)in_sizes; (void)n_in; (void)out_size; (void)ws_size;
    const float* X        = (const float*)d_in[0];
    const float* h0       = (const float*)d_in[1];
    const float* hu_grid  = (const float*)d_in[2];
    const float* hu_coef  = (const float*)d_in[3];
    const float* hu_sb    = (const float*)d_in[4];
    const float* hu_ssp   = (const float*)d_in[5];
    const float* out_grid = (const float*)d_in[6];
    const float* out_coef = (const float*)d_in[7];
    const float* out_sb   = (const float*)d_in[8];
    const float* out_ssp  = (const float*)d_in[9];
    float* out = (float*)d_out;
    float* ws  = (float*)d_ws;

    hipLaunchKernelGGL(build1_kernel, dim3(2048), dim3(256), 0, stream,
                       hu_coef, hu_sb, hu_ssp, ws);
    hipLaunchKernelGGL(xpart_kernel, dim3(SEQ/R1), dim3(256), 0, stream, X, hu_grid, ws);
    hipLaunchKernelGGL(seq_kernel, dim3(NB_LAUNCH), dim3(TPB2), 0, stream, h0, hu_grid, ws, out);
    hipLaunchKernelGGL(build2_kernel, dim3(1024), dim3(256), 0, stream,
                       out_coef, out_sb, out_ssp, ws);
    hipLaunchKernelGGL(outlayer_kernel, dim3(SEQ/R3), dim3(256), 0, stream, out_grid, ws, out);
}

// Round 9
// 51846.118 us; speedup vs baseline: 1.0455x; 1.0455x over previous
//
#include <hip/hip_runtime.h>
#include <math.h>

#define SEQ 8192
#define IN_DIM 128
#define HID 512
#define OUT_DIM 128
#define NK 9      // 8 spline basis + 1 silu slot
#define KNOTS 12

// ws layout (floats). W9HU region reused for W9O by build2 (after seq).
#define WS_ELECT 0                           // [0]=ticket, [1..32]=slot xcc (u32)
#define WS_W9HU  64                          // 128*9*512 = 589,824 (xpart W); later W9O (512*9*128)
#define WS_WSEQ  (WS_W9HU + 589824)          // 32*128*4*4*4*9 = 2,359,296 (seq W: [blk][q][oq][r][j][k])
#define WS_XPART (WS_WSEQ + 2359296)         // 8192*512
#define WS_HCOMM (WS_XPART + 4194304)        // 8192*512
#define WS_TOTAL (WS_HCOMM + 4194304)        // ~45.4 MB

#define SENTINEL 0x7FA0DEADu   // sNaN payload; never produced by arithmetic
#define SLOT_INIT 0xFFFFFFFFu

#define NWG 32
#define TPB2 512
#define NB_LAUNCH 512

__device__ __forceinline__ int brow(int ib) { return ib*3 + (ib >> 4); }  // R2-proven (stride-16 reads)
// bijective row permutation for seq LDS (R8-proven correct)
__device__ __forceinline__ int rho(int i) { return i ^ ((i >> 4) & 7); }

// L1-bypassing load: hits this XCD's L2 (same-XCD coherence point)
__device__ __forceinline__ unsigned ld_sc0(const unsigned* p) {
    unsigned r;
    asm volatile("global_load_dword %0, %1, off sc0\n\ts_waitcnt vmcnt(0)"
                 : "=v"(r) : "v"(p) : "memory");
    return r;
}

__device__ __forceinline__ void load_knots(const float* gptr, float* g, float* invA) {
    #pragma unroll
    for (int j = 0; j < KNOTS; ++j) g[j] = gptr[j];
    #pragma unroll
    for (int d = 1; d <= 3; ++d) {
        #pragma unroll
        for (int j = 0; j < 11; ++j) {
            if (j + d <= 11) invA[(d-1)*11 + j] = 1.0f / (g[j+d] - g[j]);
        }
    }
}

// Exact Cox-de Boor (degree 3) + silu — parallel kernels (R2-proven)
__device__ __forceinline__ void basis9(float x, const float* g, const float* invA, float* out) {
    float B[11];
    #pragma unroll
    for (int j = 0; j < 11; ++j)
        B[j] = (x >= g[j] && x < g[j+1]) ? 1.0f : 0.0f;
    #pragma unroll
    for (int d = 1; d <= 3; ++d) {
        #pragma unroll
        for (int j = 0; j < 11; ++j) {
            if (j + d < 11) {
                float left  = (x - g[j]) * invA[(d-1)*11 + j];
                float right = (g[j+d+1] - x) * invA[(d-1)*11 + j + 1];
                B[j] = left * B[j] + right * B[j+1];
            }
        }
    }
    #pragma unroll
    for (int j = 0; j < 8; ++j) out[j] = B[j];
    out[8] = x / (1.0f + expf(-x));
}

// ---------------- build1: election init + xpart weights + seq weights + sentinel fill ----------------
__global__ __launch_bounds__(256) void build1_kernel(
    const float* __restrict__ hu_coef, const float* __restrict__ hu_sb, const float* __restrict__ hu_ssp,
    float* __restrict__ ws)
{
    int idx = blockIdx.x * blockDim.x + threadIdx.x;
    int stride = gridDim.x * blockDim.x;
    if (idx == 0) ((unsigned*)ws)[0] = 0u;
    else if (idx <= 32) ((unsigned*)ws)[idx] = SLOT_INIT;
    const int N1 = 128 * 9 * 512;
    for (int p = idx; p < N1; p += stride) {
        int o = p & 511; int k = (p >> 9) % 9; int i = p / 4608;
        float v = (k < 8) ? hu_ssp[i*HID + o] * hu_coef[(i*HID + o)*8 + k] : hu_sb[i*HID + o];
        ws[WS_W9HU + p] = v;
    }
    const int N2 = 32 * 128 * 4 * 4 * 4 * 9;
    for (int p = idx; p < N2; p += stride) {
        int k = p % 9; int rest = p / 9;
        int j = rest & 3; rest >>= 2;
        int r = rest & 3; rest >>= 2;
        int oq = rest & 3; rest >>= 2;
        int q = rest & 127; int blk = rest >> 7;
        int gi = IN_DIM + 4*q + r;
        int o  = blk*16 + oq*4 + j;
        float v = (k < 8) ? hu_ssp[gi*HID + o] * hu_coef[(gi*HID + o)*8 + k] : hu_sb[gi*HID + o];
        ws[WS_WSEQ + p] = v;
    }
    unsigned* hc = (unsigned*)(ws + WS_HCOMM);
    for (int p = idx; p < SEQ*HID; p += stride) hc[p] = SENTINEL;
}

// ---------------- build2: output-layer weights (overlays W9HU; runs after seq) ----------------
__global__ __launch_bounds__(256) void build2_kernel(
    const float* __restrict__ out_coef, const float* __restrict__ out_sb, const float* __restrict__ out_ssp,
    float* __restrict__ ws)
{
    int idx = blockIdx.x * blockDim.x + threadIdx.x;
    int stride = gridDim.x * blockDim.x;
    const int N = 512 * 9 * 128;   // [i<512][k<9][o<128]
    for (int p = idx; p < N; p += stride) {
        int o = p & 127; int k = (p >> 7) % 9; int i = p / 1152;
        float v = (k < 8) ? out_ssp[i*OUT_DIM + o] * out_coef[(i*OUT_DIM + o)*8 + k] : out_sb[i*OUT_DIM + o];
        ws[WS_W9HU + p] = v;
    }
}

// ---------------- phase 1: x-part contributions (R2-proven form) ----------------
#define R1 4
__global__ __launch_bounds__(256) void xpart_kernel(
    const float* __restrict__ X, const float* __restrict__ hu_grid, float* __restrict__ ws)
{
    const int tid = threadIdx.x;
    const int t0 = blockIdx.x * R1;
    const float* W9 = ws + WS_W9HU;
    float* xpart = ws + WS_XPART;
    float g[KNOTS], invA[33];
    load_knots(hu_grid, g, invA);

    __shared__ float4 bas4[R1*IN_DIM*3 + (R1*IN_DIM)/16];
    #pragma unroll
    for (int rep = 0; rep < 2; ++rep) {
        int idx = tid + rep*256;
        int r = idx >> 7, i = idx & 127;
        float bv[9];
        basis9(X[(t0 + r)*IN_DIM + i], g, invA, bv);
        int rb = brow(idx);
        bas4[rb]   = make_float4(bv[0], bv[1], bv[2], bv[3]);
        bas4[rb+1] = make_float4(bv[4], bv[5], bv[6], bv[7]);
        bas4[rb+2] = make_float4(bv[8], 0.f, 0.f, 0.f);
    }
    __syncthreads();

    float acc[R1][2];
    #pragma unroll
    for (int r = 0; r < R1; ++r) { acc[r][0] = 0.f; acc[r][1] = 0.f; }

    for (int i = 0; i < IN_DIM; ++i) {
        float w1[9], w2[9];
        #pragma unroll
        for (int k = 0; k < 9; ++k) {
            w1[k] = W9[(i*NK+k)*HID + tid];
            w2[k] = W9[(i*NK+k)*HID + tid + 256];
        }
        #pragma unroll
        for (int r = 0; r < R1; ++r) {
            const float* rp = (const float*)&bas4[brow(r*IN_DIM + i)];
            float4 b0 = ((const float4*)rp)[0], b1 = ((const float4*)rp)[1];
            float b8 = rp[8];
            float s1 = w1[0]*b0.x + w1[1]*b0.y + w1[2]*b0.z + w1[3]*b0.w
                     + w1[4]*b1.x + w1[5]*b1.y + w1[6]*b1.z + w1[7]*b1.w + w1[8]*b8;
            float s2 = w2[0]*b0.x + w2[1]*b0.y + w2[2]*b0.z + w2[3]*b0.w
                     + w2[4]*b1.x + w2[5]*b1.y + w2[6]*b1.z + w2[7]*b1.w + w2[8]*b8;
            acc[r][0] += s1; acc[r][1] += s2;
        }
    }
    #pragma unroll
    for (int r = 0; r < R1; ++r) {
        xpart[(t0+r)*HID + tid]       = acc[r][0];
        xpart[(t0+r)*HID + tid + 256] = acc[r][1];
    }
}

// ---- named-register weight machinery (no array -> nothing to spill) ----
#define FOR_RJ(F) F(0,0) F(0,1) F(0,2) F(0,3) \
                  F(1,0) F(1,1) F(1,2) F(1,3) \
                  F(2,0) F(2,1) F(2,2) F(2,3) \
                  F(3,0) F(3,1) F(3,2) F(3,3)
#define DECLW(r,j) float4 Wa##r##j, Wb##r##j; float Wc##r##j;
#define LOADW(r,j) { const float* _p = Wptr + ((r)*4+(j))*9; \
    Wa##r##j = make_float4(_p[0],_p[1],_p[2],_p[3]); \
    Wb##r##j = make_float4(_p[4],_p[5],_p[6],_p[7]); \
    Wc##r##j = _p[8]; }
#define MACRJ(r,j,pj) pj += Wa##r##j.x*b0.x + Wa##r##j.y*b0.y + Wa##r##j.z*b0.z + Wa##r##j.w*b0.w \
                          + Wb##r##j.x*b1.x + Wb##r##j.y*b1.y + Wb##r##j.z*b1.z + Wb##r##j.w*b1.w \
                          + Wc##r##j*b8;
#define MACROW(r) { const float* rp = basf + rho(4*q + r)*12; \
    float4 b0 = ((const float4*)rp)[0], b1 = ((const float4*)rp)[1]; \
    float b8 = rp[8]; \
    MACRJ(r,0,p0) MACRJ(r,1,p1) MACRJ(r,2,p2) MACRJ(r,3,p3) }

// ---------------- phase 2: sequential recurrence (same-XCD cluster; named-reg weights) ----------------
__global__ __attribute__((amdgpu_flat_work_group_size(TPB2, TPB2), amdgpu_waves_per_eu(2, 2)))
void seq_kernel(
    const float* __restrict__ h0, const float* __restrict__ hu_grid,
    float* __restrict__ ws, float* __restrict__ d_out)
{
    __shared__ int sh_slot, sh_mode;
    __shared__ float basf[512*12];          // rho-permuted rows, stride 12 floats (16B-aligned)
    __shared__ float red[8][4][4];

    const int tid = threadIdx.x;
    unsigned* el = (unsigned*)ws;

    if (tid == 0) {
        unsigned xcc;
        asm volatile("s_getreg_b32 %0, hwreg(HW_REG_XCC_ID)" : "=s"(xcc));
        int slot = 64;
        if (xcc == 0u) {
            slot = (int)__hip_atomic_fetch_add(&el[0], 1u, __ATOMIC_RELAXED, __HIP_MEMORY_SCOPE_AGENT);
        } else {
            unsigned long long tc0 = __builtin_amdgcn_s_memrealtime();
            while (__builtin_amdgcn_s_memrealtime() - tc0 < 2500ull) {}   // ~25us, time-based only
            unsigned c = __hip_atomic_load(&el[0], __ATOMIC_RELAXED, __HIP_MEMORY_SCOPE_AGENT);
            if (c < (unsigned)NWG)
                slot = (int)__hip_atomic_fetch_add(&el[0], 1u, __ATOMIC_RELAXED, __HIP_MEMORY_SCOPE_AGENT);
        }
        int mode = 0;
        if (slot < NWG) {
            __hip_atomic_store(&el[1+slot], xcc, __ATOMIC_RELAXED, __HIP_MEMORY_SCOPE_AGENT);
            int ok = 1; unsigned first = 0;
            for (int i = 0; i < NWG; ++i) {
                unsigned v; int sp = 0;
                do { v = __hip_atomic_load(&el[1+i], __ATOMIC_RELAXED, __HIP_MEMORY_SCOPE_AGENT); }
                while (v == SLOT_INIT && ++sp < (1 << 20));
                if (v == SLOT_INIT) { ok = 0; break; }
                if (i == 0) first = v;
                else if (v != first) { ok = 0; break; }
            }
            mode = ok;
        }
        sh_slot = slot; sh_mode = mode;
    }
    __syncthreads();
    const int blk = sh_slot;
    const int mode = sh_mode;
    if (blk >= NWG) return;

    const int lane = tid & 63;
    const int wave = tid >> 6;
    const int oq   = tid & 3;        // output quad (4-way broadcast rows)
    const int q    = tid >> 2;       // input quad 0..127
    const float* xpart = ws + WS_XPART;
    float* hcomm = ws + WS_HCOMM;
    float* hs_out = d_out + (size_t)SEQ*OUT_DIM;
    const float g0 = hu_grid[0];
    const float inv_h = 1.0f / (hu_grid[1] - hu_grid[0]);

    // named-register weights: 16 (r,j) groups x (float4+float4+float) = 144 VGPRs
    FOR_RJ(DECLW)
    {
        const float* Wptr = ws + WS_WSEQ + ((size_t)((blk*128 + q)*4 + oq))*144;
        FOR_RJ(LOADW)
    }

    for (int t = 0; t < SEQ; ++t) {
        float xf = (tid < 16) ? xpart[(size_t)t*HID + blk*16 + tid] : 0.0f;  // poll-independent

        float hv;
        if (t == 0) {
            hv = h0[tid];
        } else {
            const unsigned* pp = (const unsigned*)&hcomm[(size_t)(t-1)*HID + tid];
            unsigned u;
            if (mode) {
                u = ld_sc0(pp);
                int sp = 0;
                while (u == SENTINEL && ++sp < 64) u = ld_sc0(pp);    // local-L2 fast path (bounded)
            } else {
                u = __hip_atomic_load(pp, __ATOMIC_RELAXED, __HIP_MEMORY_SCOPE_AGENT);
            }
            int sp2 = 0;
            while (u == SENTINEL && ++sp2 < (1 << 24))                // always-correct fallback
                u = __hip_atomic_load(pp, __ATOMIC_RELAXED, __HIP_MEMORY_SCOPE_AGENT);
            hv = __uint_as_float(u);
        }

        // closed-form uniform cubic basis -> LDS row rho(tid), stride 12 floats
        {
            float* rowp = basf + rho(tid)*12;
            float tq = (hv - g0) * inv_h;
            float cf = floorf(tq);
            float u  = tq - cf;
            int   c  = (int)cf;
            float si = hv * __builtin_amdgcn_rcpf(1.0f + __expf(-hv));
            ((float4*)rowp)[0] = make_float4(0.f, 0.f, 0.f, 0.f);
            ((float4*)rowp)[1] = make_float4(0.f, 0.f, 0.f, 0.f);
            rowp[8] = si;
            if (c >= 0 && c <= 10) {
                float um = 1.0f - u, u2 = u*u, u3 = u2*u;
                float P0 = um*um*um*(1.0f/6.0f);
                float P1 = 0.5f*u3 - u2 + (2.0f/3.0f);
                float P2 = -0.5f*u3 + 0.5f*u2 + 0.5f*u + (1.0f/6.0f);
                float P3 = u3*(1.0f/6.0f);
                int j0 = c - 3;
                if (j0     >= 0)              rowp[j0]     = P0;
                if (j0 + 1 >= 0 && j0+1 <= 7) rowp[j0 + 1] = P1;
                if (j0 + 2 >= 0 && j0+2 <= 7) rowp[j0 + 2] = P2;
                if (j0 + 3 <= 7)              rowp[j0 + 3] = P3;
            }
        }
        __syncthreads();

        float p0 = 0.f, p1 = 0.f, p2 = 0.f, p3 = 0.f;
        MACROW(0) MACROW(1) MACROW(2) MACROW(3)

        #pragma unroll
        for (int d = 4; d < 64; d <<= 1) {
            p0 += __shfl_xor(p0, d, 64);
            p1 += __shfl_xor(p1, d, 64);
            p2 += __shfl_xor(p2, d, 64);
            p3 += __shfl_xor(p3, d, 64);
        }
        if (lane < 4) {
            red[wave][lane][0] = p0;
            red[wave][lane][1] = p1;
            red[wave][lane][2] = p2;
            red[wave][lane][3] = p3;
        }
        __syncthreads();
        if (tid < 16) {
            float s = xf;
            #pragma unroll
            for (int wv = 0; wv < 8; ++wv) s += red[wv][tid>>2][tid&3];
            unsigned su = __float_as_uint(s);
            unsigned* dst = (unsigned*)&hcomm[(size_t)t*HID + blk*16 + tid];
            *(volatile unsigned*)dst = su;   // fast path: lands in local L2 (L1 write-through)
            __hip_atomic_store(dst, su, __ATOMIC_RELAXED, __HIP_MEMORY_SCOPE_AGENT);  // IF$: always-correct
            hs_out[(size_t)t*HID + blk*16 + tid] = s;
        }
        __syncthreads();   // WAR: basf/red rewritten next step
    }
}

// ---------------- phase 3: output layer (R2-proven form) ----------------
#define R3 2
__global__ __launch_bounds__(256) void outlayer_kernel(
    const float* __restrict__ out_grid, float* __restrict__ ws, float* __restrict__ d_out)
{
    const int tid = threadIdx.x;
    const int t0 = blockIdx.x * R3;
    const float* W9o = ws + WS_W9HU;   // overlaid by build2
    const float* hs = d_out + (size_t)SEQ*OUT_DIM;
    float g[KNOTS], invA[33];
    load_knots(out_grid, g, invA);

    __shared__ float4 bas4[R3*HID*3 + (R3*HID)/16];
    #pragma unroll
    for (int rep = 0; rep < 4; ++rep) {
        int idx = tid + rep*256;
        int r = idx >> 9, i = idx & 511;
        float bv[9];
        basis9(hs[(size_t)(t0+r)*HID + i], g, invA, bv);
        int rb = brow(idx);
        bas4[rb]   = make_float4(bv[0], bv[1], bv[2], bv[3]);
        bas4[rb+1] = make_float4(bv[4], bv[5], bv[6], bv[7]);
        bas4[rb+2] = make_float4(bv[8], 0.f, 0.f, 0.f);
    }
    __syncthreads();

    const int oo = tid & 127;
    const int half = tid >> 7;
    float acc[R3] = {0.f, 0.f};
    for (int ii = 0; ii < 256; ++ii) {
        int i = half*256 + ii;
        float wv[9];
        #pragma unroll
        for (int k = 0; k < 9; ++k) wv[k] = W9o[(i*NK+k)*OUT_DIM + oo];
        #pragma unroll
        for (int r = 0; r < R3; ++r) {
            const float* rp = (const float*)&bas4[brow(r*HID + i)];
            float4 b0 = ((const float4*)rp)[0], b1 = ((const float4*)rp)[1];
            float b8 = rp[8];
            acc[r] += wv[0]*b0.x + wv[1]*b0.y + wv[2]*b0.z + wv[3]*b0.w
                    + wv[4]*b1.x + wv[5]*b1.y + wv[6]*b1.z + wv[7]*b1.w + wv[8]*b8;
        }
    }
    __shared__ float red[2][R3][128];
    red[half][0][oo] = acc[0];
    red[half][1][oo] = acc[1];
    __syncthreads();
    {
        int rr = tid >> 7, o2 = tid & 127;
        d_out[(size_t)(t0+rr)*OUT_DIM + o2] = red[0][rr][o2] + red[1][rr][o2];
    }
}

extern "C" void kernel_launch(void* const* d_in, const int* in_sizes, int n_in,
                              void* d_out, int out_size, void* d_ws, size_t ws_size,
                              hipStream_t stream) {
    (void)in_sizes; (void)n_in; (void)out_size; (void)ws_size;
    const float* X        = (const float*)d_in[0];
    const float* h0       = (const float*)d_in[1];
    const float* hu_grid  = (const float*)d_in[2];
    const float* hu_coef  = (const float*)d_in[3];
    const float* hu_sb    = (const float*)d_in[4];
    const float* hu_ssp   = (const float*)d_in[5];
    const float* out_grid = (const float*)d_in[6];
    const float* out_coef = (const float*)d_in[7];
    const float* out_sb   = (const float*)d_in[8];
    const float* out_ssp  = (const float*)d_in[9];
    float* out = (float*)d_out;
    float* ws  = (float*)d_ws;

    hipLaunchKernelGGL(build1_kernel, dim3(2048), dim3(256), 0, stream,
                       hu_coef, hu_sb, hu_ssp, ws);
    hipLaunchKernelGGL(xpart_kernel, dim3(SEQ/R1), dim3(256), 0, stream, X, hu_grid, ws);
    hipLaunchKernelGGL(seq_kernel, dim3(NB_LAUNCH), dim3(TPB2), 0, stream, h0, hu_grid, ws, out);
    hipLaunchKernelGGL(build2_kernel, dim3(1024), dim3(256), 0, stream,
                       out_coef, out_sb, out_ssp, ws);
    hipLaunchKernelGGL(outlayer_kernel, dim3(SEQ/R3), dim3(256), 0, stream, out_grid, ws, out);
}

// Round 10
// 16750.916 us; speedup vs baseline: 3.2358x; 3.0951x over previous
//
#include <hip/hip_runtime.h>
#include <math.h>

#define SEQ 8192
#define IN_DIM 128
#define HID 512
#define OUT_DIM 128
#define NK 9      // 8 spline basis + 1 silu slot
#define KNOTS 12

// ws layout (floats). W9HU region reused for W9O by build2 (after seq).
#define WS_W9HU  0                           // 128*9*512 = 589,824 (xpart W); later W9O (512*9*128)
#define WS_WSEQP 589824                      // 32*512*72 = 1,179,648 packed bf16-pair weights (as u32)
#define WS_XPART (WS_WSEQP + 1179648)        // 8192*512
#define WS_HCOMM (WS_XPART + 4194304)        // 8192*512
#define WS_TOTAL (WS_HCOMM + 4194304)        // 10,158,080 floats = 40.6 MB

#define SENTINEL 0x7FA0DEADu   // sNaN payload; never produced by arithmetic

#define NWG 32
#define TPB2 512

__device__ __forceinline__ int brow(int ib) { return ib*3 + (ib >> 4); }  // R2-proven (stride-16 reads)
// seq LDS dword-offset: injective, monotone; stride-4-row reads cover all 8 bank-quads (2-way max)
__device__ __forceinline__ int boff(int row) { return row*12 + ((row >> 2) << 2); }

__device__ __forceinline__ unsigned bf16rne(float f) {
    unsigned b = __float_as_uint(f);
    return (b + 0x7fffu + ((b >> 16) & 1u)) >> 16;
}
__device__ __forceinline__ float blo(unsigned p) { return __uint_as_float(p << 16); }
__device__ __forceinline__ float bhi(unsigned p) { return __uint_as_float(p & 0xffff0000u); }

__device__ __forceinline__ void load_knots(const float* gptr, float* g, float* invA) {
    #pragma unroll
    for (int j = 0; j < KNOTS; ++j) g[j] = gptr[j];
    #pragma unroll
    for (int d = 1; d <= 3; ++d) {
        #pragma unroll
        for (int j = 0; j < 11; ++j) {
            if (j + d <= 11) invA[(d-1)*11 + j] = 1.0f / (g[j+d] - g[j]);
        }
    }
}

// Exact Cox-de Boor (degree 3) + silu — parallel kernels (R2-proven)
__device__ __forceinline__ void basis9(float x, const float* g, const float* invA, float* out) {
    float B[11];
    #pragma unroll
    for (int j = 0; j < 11; ++j)
        B[j] = (x >= g[j] && x < g[j+1]) ? 1.0f : 0.0f;
    #pragma unroll
    for (int d = 1; d <= 3; ++d) {
        #pragma unroll
        for (int j = 0; j < 11; ++j) {
            if (j + d < 11) {
                float left  = (x - g[j]) * invA[(d-1)*11 + j];
                float right = (g[j+d+1] - x) * invA[(d-1)*11 + j + 1];
                B[j] = left * B[j] + right * B[j+1];
            }
        }
    }
    #pragma unroll
    for (int j = 0; j < 8; ++j) out[j] = B[j];
    out[8] = x / (1.0f + expf(-x));
}

// ---------------- build1: xpart weights + packed seq weights + sentinel fill ----------------
__global__ __launch_bounds__(256) void build1_kernel(
    const float* __restrict__ hu_coef, const float* __restrict__ hu_sb, const float* __restrict__ hu_ssp,
    float* __restrict__ ws)
{
    int idx = blockIdx.x * blockDim.x + threadIdx.x;
    int stride = gridDim.x * blockDim.x;
    // xpart slab: [i<128][k<9][o<512]
    const int N1 = 128 * 9 * 512;
    for (int p = idx; p < N1; p += stride) {
        int o = p & 511; int k = (p >> 9) % 9; int i = p / 4608;
        float v = (k < 8) ? hu_ssp[i*HID + o] * hu_coef[(i*HID + o)*8 + k] : hu_sb[i*HID + o];
        ws[WS_W9HU + p] = v;
    }
    // packed seq slab: [blk<32][th<512][slot<72]
    unsigned* WP = (unsigned*)(ws + WS_WSEQP);
    const int N2 = 32 * 512 * 72;
    for (int p = idx; p < N2; p += stride) {
        int slot = p % 72; int th = (p / 72) & 511; int blk = p / (72 * 512);
        int q = th >> 2, oq = th & 3;
        unsigned pr;
        if (slot < 64) {
            int r = slot >> 4, j = (slot >> 2) & 3, kp = slot & 3;
            int gi = IN_DIM + 4*q + r;
            int o  = blk*16 + oq*4 + j;
            float wlo = hu_ssp[gi*HID + o] * hu_coef[(gi*HID + o)*8 + 2*kp];
            float whi = hu_ssp[gi*HID + o] * hu_coef[(gi*HID + o)*8 + 2*kp + 1];
            pr = bf16rne(wlo) | (bf16rne(whi) << 16);
        } else {
            int e = slot - 64;
            int r = e >> 1, jp = e & 1;
            int gi = IN_DIM + 4*q + r;
            int o0 = blk*16 + oq*4 + 2*jp;
            int o1 = o0 + 1;
            pr = bf16rne(hu_sb[gi*HID + o0]) | (bf16rne(hu_sb[gi*HID + o1]) << 16);
        }
        WP[p] = pr;
    }
    // sentinel fill
    unsigned* hc = (unsigned*)(ws + WS_HCOMM);
    for (int p = idx; p < SEQ*HID; p += stride) hc[p] = SENTINEL;
}

// ---------------- build2: output-layer weights (overlays W9HU; runs after seq) ----------------
__global__ __launch_bounds__(256) void build2_kernel(
    const float* __restrict__ out_coef, const float* __restrict__ out_sb, const float* __restrict__ out_ssp,
    float* __restrict__ ws)
{
    int idx = blockIdx.x * blockDim.x + threadIdx.x;
    int stride = gridDim.x * blockDim.x;
    const int N = 512 * 9 * 128;   // [i<512][k<9][o<128]
    for (int p = idx; p < N; p += stride) {
        int o = p & 127; int k = (p >> 7) % 9; int i = p / 1152;
        float v = (k < 8) ? out_ssp[i*OUT_DIM + o] * out_coef[(i*OUT_DIM + o)*8 + k] : out_sb[i*OUT_DIM + o];
        ws[WS_W9HU + p] = v;
    }
}

// ---------------- phase 1: x-part contributions (R2-proven form) ----------------
#define R1 4
__global__ __launch_bounds__(256) void xpart_kernel(
    const float* __restrict__ X, const float* __restrict__ hu_grid, float* __restrict__ ws)
{
    const int tid = threadIdx.x;
    const int t0 = blockIdx.x * R1;
    const float* W9 = ws + WS_W9HU;
    float* xpart = ws + WS_XPART;
    float g[KNOTS], invA[33];
    load_knots(hu_grid, g, invA);

    __shared__ float4 bas4[R1*IN_DIM*3 + (R1*IN_DIM)/16];
    #pragma unroll
    for (int rep = 0; rep < 2; ++rep) {
        int idx = tid + rep*256;
        int r = idx >> 7, i = idx & 127;
        float bv[9];
        basis9(X[(t0 + r)*IN_DIM + i], g, invA, bv);
        int rb = brow(idx);
        bas4[rb]   = make_float4(bv[0], bv[1], bv[2], bv[3]);
        bas4[rb+1] = make_float4(bv[4], bv[5], bv[6], bv[7]);
        bas4[rb+2] = make_float4(bv[8], 0.f, 0.f, 0.f);
    }
    __syncthreads();

    float acc[R1][2];
    #pragma unroll
    for (int r = 0; r < R1; ++r) { acc[r][0] = 0.f; acc[r][1] = 0.f; }

    for (int i = 0; i < IN_DIM; ++i) {
        float w1[9], w2[9];
        #pragma unroll
        for (int k = 0; k < 9; ++k) {
            w1[k] = W9[(i*NK+k)*HID + tid];
            w2[k] = W9[(i*NK+k)*HID + tid + 256];
        }
        #pragma unroll
        for (int r = 0; r < R1; ++r) {
            const float* rp = (const float*)&bas4[brow(r*IN_DIM + i)];
            float4 b0 = ((const float4*)rp)[0], b1 = ((const float4*)rp)[1];
            float b8 = rp[8];
            float s1 = w1[0]*b0.x + w1[1]*b0.y + w1[2]*b0.z + w1[3]*b0.w
                     + w1[4]*b1.x + w1[5]*b1.y + w1[6]*b1.z + w1[7]*b1.w + w1[8]*b8;
            float s2 = w2[0]*b0.x + w2[1]*b0.y + w2[2]*b0.z + w2[3]*b0.w
                     + w2[4]*b1.x + w2[5]*b1.y + w2[6]*b1.z + w2[7]*b1.w + w2[8]*b8;
            acc[r][0] += s1; acc[r][1] += s2;
        }
    }
    #pragma unroll
    for (int r = 0; r < R1; ++r) {
        xpart[(t0+r)*HID + tid]       = acc[r][0];
        xpart[(t0+r)*HID + tid + 256] = acc[r][1];
    }
}

// ---------------- phase 2: sequential recurrence (R6 skeleton; bf16-packed reg weights) ----------------
__global__ __launch_bounds__(TPB2, 1) void seq_kernel(
    const float* __restrict__ h0, const float* __restrict__ hu_grid,
    const unsigned* __restrict__ WP,      // packed weights slab
    const float* __restrict__ xpart,
    unsigned* __restrict__ hcomm,         // u32 view of comm slab
    float* __restrict__ hs_out)
{
    const int tid  = threadIdx.x;
    const int blk  = blockIdx.x;
    const int lane = tid & 63;
    const int wave = tid >> 6;
    const int oq   = tid & 3;        // output quad (4-way broadcast rows)
    const int q    = tid >> 2;       // input quad 0..127
    const float g0 = hu_grid[0];
    const float inv_h = 1.0f / (hu_grid[1] - hu_grid[0]);

    // packed register-resident weights: 64 spline pairs + 8 silu pairs = 72 u32
    unsigned wsp[4][4][4];   // [r][j][kp]
    unsigned wsl[4][2];      // [r][jp]
    {
        const uint4* Wb = (const uint4*)(WP + ((size_t)blk*512 + tid)*72);
        #pragma unroll
        for (int r = 0; r < 4; ++r) {
            #pragma unroll
            for (int j = 0; j < 4; ++j) {
                uint4 v = Wb[r*4 + j];
                wsp[r][j][0] = v.x; wsp[r][j][1] = v.y; wsp[r][j][2] = v.z; wsp[r][j][3] = v.w;
            }
        }
        uint4 s0 = Wb[16];      // slots 64..67
        uint4 s1 = Wb[17];      // slots 68..71
        wsl[0][0]=s0.x; wsl[0][1]=s0.y; wsl[1][0]=s0.z; wsl[1][1]=s0.w;
        wsl[2][0]=s1.x; wsl[2][1]=s1.y; wsl[3][0]=s1.z; wsl[3][1]=s1.w;
    }

    __shared__ float basf[6656];
    __shared__ float red[8][4][4];

    for (int t = 0; t < SEQ; ++t) {
        float xf = (tid < 16) ? xpart[(size_t)t*HID + blk*16 + tid] : 0.0f;  // poll-independent

        float hv;
        if (t == 0) {
            hv = h0[tid];
        } else {
            const unsigned* pp = &hcomm[(size_t)(t-1)*HID + tid];
            unsigned u = __hip_atomic_load(pp, __ATOMIC_RELAXED, __HIP_MEMORY_SCOPE_AGENT);
            int sp = 0;
            while (u == SENTINEL && ++sp < (1 << 24))
                u = __hip_atomic_load(pp, __ATOMIC_RELAXED, __HIP_MEMORY_SCOPE_AGENT);
            hv = __uint_as_float(u);
        }

        // closed-form uniform cubic basis -> LDS row boff(tid)
        {
            float* rowp = basf + boff(tid);
            float tq = (hv - g0) * inv_h;
            float cf = floorf(tq);
            float u  = tq - cf;
            int   c  = (int)cf;
            float si = hv * __builtin_amdgcn_rcpf(1.0f + __expf(-hv));
            ((float4*)rowp)[0] = make_float4(0.f, 0.f, 0.f, 0.f);
            ((float4*)rowp)[1] = make_float4(0.f, 0.f, 0.f, 0.f);
            rowp[8] = si;
            if (c >= 0 && c <= 10) {
                float um = 1.0f - u, u2 = u*u, u3 = u2*u;
                float P0 = um*um*um*(1.0f/6.0f);
                float P1 = 0.5f*u3 - u2 + (2.0f/3.0f);
                float P2 = -0.5f*u3 + 0.5f*u2 + 0.5f*u + (1.0f/6.0f);
                float P3 = u3*(1.0f/6.0f);
                int j0 = c - 3;
                if (j0     >= 0)              rowp[j0]     = P0;
                if (j0 + 1 >= 0 && j0+1 <= 7) rowp[j0 + 1] = P1;
                if (j0 + 2 >= 0 && j0+2 <= 7) rowp[j0 + 2] = P2;
                if (j0 + 3 <= 7)              rowp[j0 + 3] = P3;
            }
        }
        __syncthreads();

        float p0 = 0.f, p1 = 0.f, p2 = 0.f, p3 = 0.f;
        #pragma unroll
        for (int r = 0; r < 4; ++r) {
            const float* rp = basf + boff(4*q + r);
            float4 b0 = ((const float4*)rp)[0], b1 = ((const float4*)rp)[1];
            float b8 = rp[8];
            p0 += blo(wsp[r][0][0])*b0.x + bhi(wsp[r][0][0])*b0.y + blo(wsp[r][0][1])*b0.z + bhi(wsp[r][0][1])*b0.w
                + blo(wsp[r][0][2])*b1.x + bhi(wsp[r][0][2])*b1.y + blo(wsp[r][0][3])*b1.z + bhi(wsp[r][0][3])*b1.w
                + blo(wsl[r][0])*b8;
            p1 += blo(wsp[r][1][0])*b0.x + bhi(wsp[r][1][0])*b0.y + blo(wsp[r][1][1])*b0.z + bhi(wsp[r][1][1])*b0.w
                + blo(wsp[r][1][2])*b1.x + bhi(wsp[r][1][2])*b1.y + blo(wsp[r][1][3])*b1.z + bhi(wsp[r][1][3])*b1.w
                + bhi(wsl[r][0])*b8;
            p2 += blo(wsp[r][2][0])*b0.x + bhi(wsp[r][2][0])*b0.y + blo(wsp[r][2][1])*b0.z + bhi(wsp[r][2][1])*b0.w
                + blo(wsp[r][2][2])*b1.x + bhi(wsp[r][2][2])*b1.y + blo(wsp[r][2][3])*b1.z + bhi(wsp[r][2][3])*b1.w
                + blo(wsl[r][1])*b8;
            p3 += blo(wsp[r][3][0])*b0.x + bhi(wsp[r][3][0])*b0.y + blo(wsp[r][3][1])*b0.z + bhi(wsp[r][3][1])*b0.w
                + blo(wsp[r][3][2])*b1.x + bhi(wsp[r][3][2])*b1.y + blo(wsp[r][3][3])*b1.z + bhi(wsp[r][3][3])*b1.w
                + bhi(wsl[r][1])*b8;
        }
        #pragma unroll
        for (int d = 4; d < 64; d <<= 1) {
            p0 += __shfl_xor(p0, d, 64);
            p1 += __shfl_xor(p1, d, 64);
            p2 += __shfl_xor(p2, d, 64);
            p3 += __shfl_xor(p3, d, 64);
        }
        if (lane < 4) {
            red[wave][lane][0] = p0;
            red[wave][lane][1] = p1;
            red[wave][lane][2] = p2;
            red[wave][lane][3] = p3;
        }
        __syncthreads();
        if (tid < 16) {
            float s = xf;
            #pragma unroll
            for (int wv = 0; wv < 8; ++wv) s += red[wv][tid>>2][tid&3];
            __hip_atomic_store(&hcomm[(size_t)t*HID + blk*16 + tid], __float_as_uint(s),
                               __ATOMIC_RELAXED, __HIP_MEMORY_SCOPE_AGENT);
            hs_out[(size_t)t*HID + blk*16 + tid] = s;
        }
        __syncthreads();   // WAR: basf/red rewritten next step
    }
}

// ---------------- phase 3: output layer (R2-proven form) ----------------
#define R3 2
__global__ __launch_bounds__(256) void outlayer_kernel(
    const float* __restrict__ out_grid, float* __restrict__ ws, float* __restrict__ d_out)
{
    const int tid = threadIdx.x;
    const int t0 = blockIdx.x * R3;
    const float* W9o = ws + WS_W9HU;   // overlaid by build2
    const float* hs = d_out + (size_t)SEQ*OUT_DIM;
    float g[KNOTS], invA[33];
    load_knots(out_grid, g, invA);

    __shared__ float4 bas4[R3*HID*3 + (R3*HID)/16];
    #pragma unroll
    for (int rep = 0; rep < 4; ++rep) {
        int idx = tid + rep*256;
        int r = idx >> 9, i = idx & 511;
        float bv[9];
        basis9(hs[(size_t)(t0+r)*HID + i], g, invA, bv);
        int rb = brow(idx);
        bas4[rb]   = make_float4(bv[0], bv[1], bv[2], bv[3]);
        bas4[rb+1] = make_float4(bv[4], bv[5], bv[6], bv[7]);
        bas4[rb+2] = make_float4(bv[8], 0.f, 0.f, 0.f);
    }
    __syncthreads();

    const int oo = tid & 127;
    const int half = tid >> 7;
    float acc[R3] = {0.f, 0.f};
    for (int ii = 0; ii < 256; ++ii) {
        int i = half*256 + ii;
        float wv[9];
        #pragma unroll
        for (int k = 0; k < 9; ++k) wv[k] = W9o[(i*NK+k)*OUT_DIM + oo];
        #pragma unroll
        for (int r = 0; r < R3; ++r) {
            const float* rp = (const float*)&bas4[brow(r*HID + i)];
            float4 b0 = ((const float4*)rp)[0], b1 = ((const float4*)rp)[1];
            float b8 = rp[8];
            acc[r] += wv[0]*b0.x + wv[1]*b0.y + wv[2]*b0.z + wv[3]*b0.w
                    + wv[4]*b1.x + wv[5]*b1.y + wv[6]*b1.z + wv[7]*b1.w + wv[8]*b8;
        }
    }
    __shared__ float red[2][R3][128];
    red[half][0][oo] = acc[0];
    red[half][1][oo] = acc[1];
    __syncthreads();
    {
        int rr = tid >> 7, o2 = tid & 127;
        d_out[(size_t)(t0+rr)*OUT_DIM + o2] = red[0][rr][o2] + red[1][rr][o2];
    }
}

extern "C" void kernel_launch(void* const* d_in, const int* in_sizes, int n_in,
                              void* d_out, int out_size, void* d_ws, size_t ws_size,
                              hipStream_t stream) {
    (void)in_sizes; (void)n_in; (void)out_size; (void)ws_size;
    const float* X        = (const float*)d_in[0];
    const float* h0       = (const float*)d_in[1];
    const float* hu_grid  = (const float*)d_in[2];
    const float* hu_coef  = (const float*)d_in[3];
    const float* hu_sb    = (const float*)d_in[4];
    const float* hu_ssp   = (const float*)d_in[5];
    const float* out_grid = (const float*)d_in[6];
    const float* out_coef = (const float*)d_in[7];
    const float* out_sb   = (const float*)d_in[8];
    const float* out_ssp  = (const float*)d_in[9];
    float* out = (float*)d_out;
    float* ws  = (float*)d_ws;

    hipLaunchKernelGGL(build1_kernel, dim3(2048), dim3(256), 0, stream,
                       hu_coef, hu_sb, hu_ssp, ws);
    hipLaunchKernelGGL(xpart_kernel, dim3(SEQ/R1), dim3(256), 0, stream, X, hu_grid, ws);
    hipLaunchKernelGGL(seq_kernel, dim3(NWG), dim3(TPB2), 0, stream,
                       h0, hu_grid,
                       (const unsigned*)(ws + WS_WSEQP),
                       ws + WS_XPART,
                       (unsigned*)(ws + WS_HCOMM),
                       out + (size_t)SEQ*OUT_DIM);
    hipLaunchKernelGGL(build2_kernel, dim3(1024), dim3(256), 0, stream,
                       out_coef, out_sb, out_ssp, ws);
    hipLaunchKernelGGL(outlayer_kernel, dim3(SEQ/R3), dim3(256), 0, stream, out_grid, ws, out);
}